// Round 10
// baseline (809.459 us; speedup 1.0000x reference)
//
#include <hip/hip_runtime.h>
#include <hip/hip_cooperative_groups.h>

namespace cg = cooperative_groups;

typedef short bf16x8 __attribute__((ext_vector_type(8)));
typedef float f32x4 __attribute__((ext_vector_type(4)));

#define NEG 0.01f

// wbf slab byte offsets (bf16, content pre-swizzled within rows: byte ^= (row&KEY)<<4, 16B granule)
#define OFF_P0  0        // [128][32]  rowB=64,  key (r&3)<<4 (pw0, k padded 16->32 with zeros)
#define OFF_P1  8192     // [128][128] rowB=256, key (r&7)<<4
#define OFF_M0  40960    // [128][128] x3 (mw0,mw1,mw2)
#define OFF_Q0A 139264   // [128][128] qw0 cols 0..127   (z3 part)
#define OFF_Q0B 172032   // [128][128] qw0 cols 128..255 (h part)
#define OFF_Q1  204800   // [64][128]
#define WBF_BYTES 221184

#define NBLK 256
#define NTHR 448
#define NWAVE 7
#define GSTRIDE (NBLK*NTHR)   // 114688; scan assumes N <= GSTRIDE
#define NWAVES_G (NBLK*NWAVE) // 1792

#define VMCNT0 asm volatile("s_waitcnt vmcnt(0)" ::: "memory")
#define LGKM0  asm volatile("s_waitcnt lgkmcnt(0)" ::: "memory")

__device__ __forceinline__ unsigned short f2bf(float f) {
  union { float f; unsigned u; } v; v.f = f;
  unsigned u = v.u;
  return (unsigned short)((u + 0x7fffu + ((u >> 16) & 1u)) >> 16);
}
__device__ __forceinline__ unsigned pack2(float a, float b) {
  return ((unsigned)f2bf(b) << 16) | (unsigned)f2bf(a);
}
__device__ __forceinline__ float bflo(unsigned u) { return __uint_as_float(u << 16); }
__device__ __forceinline__ float bfhi(unsigned u) { return __uint_as_float(u & 0xffff0000u); }
__device__ __forceinline__ float lrelu(float v) { return fmaxf(v, 0.0f) + NEG * fminf(v, 0.0f); }
__device__ __forceinline__ float tanh_fast(float x) {
  float e = __expf(2.0f * x);
  return 1.0f - __fdividef(2.0f, e + 1.0f);
}

__device__ __forceinline__ void gll16(const void* g, void* l) {
  __builtin_amdgcn_global_load_lds((const __attribute__((address_space(1))) void*)g,
                                   (__attribute__((address_space(3))) void*)l, 16, 0, 0);
}
__device__ __forceinline__ void gll_lin(const char* g, char* l, int nchunks, int wvi, int lane) {
  for (int j = wvi; j < nchunks; j += NWAVE)
    gll16(g + j * 1024 + lane * 16, l + j * 1024 + lane * 16);
}
__device__ __forceinline__ void gll_rows(const char* gsrc, char* scr, int strip, int N, int lane) {
  #pragma unroll
  for (int c = 0; c < 8; ++c) {
    int L = c * 1024 + lane * 16;
    int row = strip + (L >> 8);
    row = row < N ? row : N - 1;
    gll16(gsrc + (size_t)row * 256 + (L & 255), scr + c * 1024 + lane * 16);
  }
}
__device__ __forceinline__ void copy_rows_out(const char* scr, char* gdst, int strip, int N, int lane) {
  #pragma unroll
  for (int c = 0; c < 8; ++c) {
    int L = c * 1024 + lane * 16;
    int row = strip + (L >> 8);
    if (row < N) *(uint4*)(gdst + (size_t)strip * 256 + L) = *(const uint4*)(scr + L);
  }
}
__device__ __forceinline__ void zacc82(f32x4 acc[8][2]) {
  #pragma unroll
  for (int m = 0; m < 8; ++m)
    #pragma unroll
    for (int n = 0; n < 2; ++n) { f32x4 z = {0.f,0.f,0.f,0.f}; acc[m][n] = z; }
}
__device__ __forceinline__ void gemm128(const char* wbase, const bf16x8 b[2][4],
                                        f32x4 acc[8][2], int l15, int lg) {
  __builtin_amdgcn_s_setprio(1);
  #pragma unroll
  for (int ks = 0; ks < 4; ++ks)
    #pragma unroll
    for (int mf = 0; mf < 8; ++mf) {
      const int row = 16*mf + l15;
      bf16x8 a = *(const bf16x8*)(wbase + row*256 + ((16*lg + 64*ks) ^ ((row&7)<<4)));
      acc[mf][0] = __builtin_amdgcn_mfma_f32_16x16x32_bf16(a, b[0][ks], acc[mf][0], 0,0,0);
      acc[mf][1] = __builtin_amdgcn_mfma_f32_16x16x32_bf16(a, b[1][ks], acc[mf][1], 0,0,0);
    }
  __builtin_amdgcn_s_setprio(0);
}
__device__ __forceinline__ void read_bfrags(const char* scr, bf16x8 b[2][4], int l15, int lg) {
  #pragma unroll
  for (int nf = 0; nf < 2; ++nf) {
    const int n = 16*nf + l15;
    #pragma unroll
    for (int ks = 0; ks < 4; ++ks)
      b[nf][ks] = *(const bf16x8*)(scr + n*256 + ((16*lg + 64*ks) ^ ((n&7)<<4)));
  }
}
template<int ACT>  // 0 lrelu, 1 tanh
__device__ __forceinline__ void ep_lds(const f32x4 acc[8][2], const float* __restrict__ bias,
                                       char* scr, int l15, int lg) {
  #pragma unroll
  for (int mf = 0; mf < 8; ++mf) {
    const int ch4 = 16*mf + 4*lg;
    const float4 bv = *(const float4*)(bias + ch4);
    #pragma unroll
    for (int nf = 0; nf < 2; ++nf) {
      const int n = 16*nf + l15;
      float v0 = acc[mf][nf][0]+bv.x, v1 = acc[mf][nf][1]+bv.y;
      float v2 = acc[mf][nf][2]+bv.z, v3 = acc[mf][nf][3]+bv.w;
      if (ACT == 0) { v0=lrelu(v0); v1=lrelu(v1); v2=lrelu(v2); v3=lrelu(v3); }
      else { v0=tanh_fast(v0); v1=tanh_fast(v1); v2=tanh_fast(v2); v3=tanh_fast(v3); }
      uint2 o = { pack2(v0,v1), pack2(v2,v3) };
      *(uint2*)(scr + n*256 + ((32*mf + 8*lg) ^ ((n&7)<<4))) = o;
    }
  }
}

// ================= the whole pipeline as ONE cooperative kernel =================
extern "C" __global__ void __launch_bounds__(NTHR, 1) mega_kernel(
    const float* __restrict__ x, const int* __restrict__ ei, const float* __restrict__ ew,
    const float* __restrict__ pw0, const float* __restrict__ pb0,
    const float* __restrict__ pw1, const float* __restrict__ pb1,
    const float* __restrict__ elw, const float* __restrict__ elb,
    const float* __restrict__ mw0, const float* __restrict__ mb0,
    const float* __restrict__ mw1, const float* __restrict__ mb1,
    const float* __restrict__ mw2, const float* __restrict__ mb2,
    const float* __restrict__ qw0, const float* __restrict__ qb0,
    const float* __restrict__ qw1, const float* __restrict__ qb1,
    float* out, char* hB, char* z3, int2* recs,
    int* deg, int* offs, int* cur, int* part, int* bases, char* wbf,
    int N, int E, int S) {
  __shared__ char wSlab[98304];        // P(40K) / M(96K) / Q(80K) per phase
  __shared__ char scr_all[NWAVE*8192]; // per-wave activation scratch (also scan LDS)
  cg::grid_group grid = cg::this_grid();
  const int tid = threadIdx.x, lane = tid & 63, wv = tid >> 6;
  const int l15 = lane & 15, lg = lane >> 4;
  const int b = blockIdx.x;
  const int gid = b*NTHR + tid;
  const int gwave = b*NWAVE + wv;
  char* scr = scr_all + wv*8192;

  // ---------- phase 0: weight pack + deg zero ----------
  if (gid < 13824) {
    int c = gid;
    const float* src = nullptr;
    int dstB = 0;
    bool zero = false;
    if (c < 512) { int r = c >> 2, q = c & 3;
      dstB = OFF_P0 + r*64 + ((q*16) ^ ((r&3)<<4));
      if (q < 2) src = pw0 + r*16 + q*8; else zero = true;
    } else if (c < 2560) { int i = c - 512, r = i >> 4, q = i & 15;
      dstB = OFF_P1 + r*256 + ((q*16) ^ ((r&7)<<4));
      src = pw1 + r*128 + q*8;
    } else if (c < 8704) { int i = c - 2560, sl = i >> 11, j = i & 2047, r = j >> 4, q = j & 15;
      const float* m = (sl==0) ? mw0 : ((sl==1) ? mw1 : mw2);
      dstB = OFF_M0 + sl*32768 + r*256 + ((q*16) ^ ((r&7)<<4));
      src = m + r*128 + q*8;
    } else if (c < 10752) { int i = c - 8704, r = i >> 4, q = i & 15;
      dstB = OFF_Q0A + r*256 + ((q*16) ^ ((r&7)<<4));
      src = qw0 + r*256 + q*8;
    } else if (c < 12800) { int i = c - 10752, r = i >> 4, q = i & 15;
      dstB = OFF_Q0B + r*256 + ((q*16) ^ ((r&7)<<4));
      src = qw0 + r*256 + 128 + q*8;
    } else { int i = c - 12800, r = i >> 4, q = i & 15;
      dstB = OFF_Q1 + r*256 + ((q*16) ^ ((r&7)<<4));
      src = qw1 + r*128 + q*8;
    }
    ushort4 lo, hi;
    if (zero) { lo.x=lo.y=lo.z=lo.w=0; hi.x=hi.y=hi.z=hi.w=0; }
    else {
      float4 a = *(const float4*)src, bb = *(const float4*)(src + 4);
      lo.x=f2bf(a.x); lo.y=f2bf(a.y); lo.z=f2bf(a.z); lo.w=f2bf(a.w);
      hi.x=f2bf(bb.x); hi.y=f2bf(bb.y); hi.z=f2bf(bb.z); hi.w=f2bf(bb.w);
    }
    *(ushort4*)(wbf + dstB) = lo;
    *(ushort4*)(wbf + dstB + 8) = hi;
  }
  for (int i = gid; i < N; i += GSTRIDE) deg[i] = 0;
  __threadfence(); grid.sync();

  // ---------- phase 1: prep (P slabs to LDS, histogram, x -> h) ----------
  gll_lin(wbf + OFF_P0, wSlab, 40, wv, lane);
  for (int e = gid; e < E; e += GSTRIDE) atomicAdd(&deg[ei[E + e]], 1);
  VMCNT0; __syncthreads();
  for (int s = gwave; s < S; s += NWAVES_G) {
    const int strip = s*32;
    bf16x8 bx[2];
    #pragma unroll
    for (int nf = 0; nf < 2; ++nf) {
      int node = strip + 16*nf + l15; node = node < N ? node : N-1;
      if (lg < 2) {
        float4 u = *(const float4*)(x + (size_t)node*16 + lg*8);
        float4 v = *(const float4*)(x + (size_t)node*16 + lg*8 + 4);
        bf16x8 t;
        t[0]=(short)f2bf(u.x); t[1]=(short)f2bf(u.y); t[2]=(short)f2bf(u.z); t[3]=(short)f2bf(u.w);
        t[4]=(short)f2bf(v.x); t[5]=(short)f2bf(v.y); t[6]=(short)f2bf(v.z); t[7]=(short)f2bf(v.w);
        bx[nf] = t;
      } else {
        bf16x8 t = {0,0,0,0,0,0,0,0}; bx[nf] = t;
      }
    }
    f32x4 acc[8][2];
    zacc82(acc);
    __builtin_amdgcn_s_setprio(1);
    #pragma unroll
    for (int mf = 0; mf < 8; ++mf) {
      const int row = 16*mf + l15;
      bf16x8 a = *(const bf16x8*)(wSlab + row*64 + ((16*lg) ^ ((row&3)<<4)));
      acc[mf][0] = __builtin_amdgcn_mfma_f32_16x16x32_bf16(a, bx[0], acc[mf][0], 0,0,0);
      acc[mf][1] = __builtin_amdgcn_mfma_f32_16x16x32_bf16(a, bx[1], acc[mf][1], 0,0,0);
    }
    __builtin_amdgcn_s_setprio(0);
    ep_lds<0>(acc, pb0, scr, l15, lg);
    bf16x8 b1[2][4];
    read_bfrags(scr, b1, l15, lg);
    zacc82(acc);
    gemm128(wSlab + 8192, b1, acc, l15, lg);
    ep_lds<1>(acc, pb1, scr, l15, lg);
    copy_rows_out(scr, hB, strip, N, lane);
  }
  __threadfence(); grid.sync();

  // ---------- phase 2: grid-wide exclusive scan of deg (N <= GSTRIDE) ----------
  int* sums = (int*)scr_all;
  const int myDeg = (gid < N) ? deg[gid] : 0;
  sums[tid] = myDeg; __syncthreads();
  for (int off = 1; off < NTHR; off <<= 1) {
    int v = sums[tid];
    int u = (tid >= off) ? sums[tid - off] : 0;
    __syncthreads();
    sums[tid] = v + u;
    __syncthreads();
  }
  const int excl = sums[tid] - myDeg;
  if (tid == NTHR-1) part[b] = sums[tid];
  __threadfence(); grid.sync();
  if (b == 0 && tid < 64) {
    int p0 = part[4*tid], p1 = part[4*tid+1], p2 = part[4*tid+2], p3 = part[4*tid+3];
    int tot = p0+p1+p2+p3, run = tot;
    #pragma unroll
    for (int off = 1; off < 64; off <<= 1) { int u = __shfl_up(run, off); if (tid >= off) run += u; }
    int le = run - tot;
    bases[4*tid]   = le;
    bases[4*tid+1] = le + p0;
    bases[4*tid+2] = le + p0 + p1;
    bases[4*tid+3] = le + p0 + p1 + p2;
  }
  __threadfence(); grid.sync();
  if (gid < N) { int o = bases[b] + excl; offs[gid] = o; cur[gid] = o; }
  __threadfence(); grid.sync();

  // ---------- phase 3: scatter edges into CSR slots ----------
  for (int e = gid; e < E; e += GSTRIDE) {
    int dst = ei[E + e];
    int slot = atomicAdd(&cur[dst], 1);
    int2 r; r.x = ei[e]; r.y = __float_as_int(ew[e]);
    recs[slot] = r;
  }
  __threadfence(); grid.sync();

  // ---------- phase 4: agg (into LDS, no zB!) + nodeA MLP -> z3 ----------
  gll_lin(wbf + OFF_M0, wSlab, 96, wv, lane);
  VMCNT0; __syncthreads();
  {
    const int half = lane >> 5, l31 = lane & 31;
    const int byteL = l31 * 8;
    const float4 wl = *(const float4*)(elw + 4*l31);
    const float4 bl = *(const float4*)(elb + 4*l31);
    for (int s = gwave; s < S; s += NWAVES_G) {
      const int strip = s*32;
      for (int pr = 0; pr < 16; ++pr) {
        const int lrow = 2*pr + half;
        const int node = strip + lrow;
        if (node < N) {
          const int s0 = offs[node], e0 = cur[node];
          float c0=0.f, c1=0.f, c2=0.f, c3=0.f;
          int j = s0;
          for (; j + 2 <= e0; j += 2) {
            int2 r0 = recs[j], r1 = recs[j+1];
            uint2 u0 = *(const uint2*)(hB + (size_t)r0.x*256 + (byteL ^ ((r0.x&7)<<4)));
            uint2 u1 = *(const uint2*)(hB + (size_t)r1.x*256 + (byteL ^ ((r1.x&7)<<4)));
            float w0 = __int_as_float(r0.y), w1 = __int_as_float(r1.y);
            c0 += fmaxf(bflo(u0.x) + w0*wl.x + bl.x, 0.f);
            c1 += fmaxf(bfhi(u0.x) + w0*wl.y + bl.y, 0.f);
            c2 += fmaxf(bflo(u0.y) + w0*wl.z + bl.z, 0.f);
            c3 += fmaxf(bfhi(u0.y) + w0*wl.w + bl.w, 0.f);
            c0 += fmaxf(bflo(u1.x) + w1*wl.x + bl.x, 0.f);
            c1 += fmaxf(bfhi(u1.x) + w1*wl.y + bl.y, 0.f);
            c2 += fmaxf(bflo(u1.y) + w1*wl.z + bl.z, 0.f);
            c3 += fmaxf(bfhi(u1.y) + w1*wl.w + bl.w, 0.f);
          }
          if (j < e0) {
            int2 r = recs[j];
            uint2 u = *(const uint2*)(hB + (size_t)r.x*256 + (byteL ^ ((r.x&7)<<4)));
            float w = __int_as_float(r.y);
            c0 += fmaxf(bflo(u.x) + w*wl.x + bl.x, 0.f);
            c1 += fmaxf(bfhi(u.x) + w*wl.y + bl.y, 0.f);
            c2 += fmaxf(bflo(u.y) + w*wl.z + bl.z, 0.f);
            c3 += fmaxf(bfhi(u.y) + w*wl.w + bl.w, 0.f);
          }
          const int swz = byteL ^ ((lrow&7)<<4);    // node&7 == lrow&7 (strip % 32 == 0)
          uint2 hs = *(const uint2*)(hB + (size_t)node*256 + swz);
          uint2 o;
          o.x = pack2(bflo(hs.x) + c0, bfhi(hs.x) + c1);
          o.y = pack2(bflo(hs.y) + c2, bfhi(hs.y) + c3);
          *(uint2*)(scr + lrow*256 + swz) = o;
        }
      }
      LGKM0;   // agg ds_writes complete before b-frag ds_reads
      bf16x8 b0[2][4];
      read_bfrags(scr, b0, l15, lg);
      f32x4 acc[8][2];
      zacc82(acc);
      gemm128(wSlab, b0, acc, l15, lg);
      ep_lds<0>(acc, mb0, scr, l15, lg);
      bf16x8 b1f[2][4];
      read_bfrags(scr, b1f, l15, lg);
      zacc82(acc);
      gemm128(wSlab + 32768, b1f, acc, l15, lg);
      ep_lds<0>(acc, mb1, scr, l15, lg);
      bf16x8 b2f[2][4];
      read_bfrags(scr, b2f, l15, lg);
      zacc82(acc);
      gemm128(wSlab + 65536, b2f, acc, l15, lg);
      ep_lds<1>(acc, mb2, scr, l15, lg);
      copy_rows_out(scr, z3, strip, N, lane);
    }
  }
  __threadfence(); grid.sync();

  // ---------- phase 5: nodeB ([z3 | h] -> post -> out) ----------
  gll_lin(wbf + OFF_Q0A, wSlab, 80, wv, lane);
  VMCNT0; __syncthreads();
  for (int s = gwave; s < S; s += NWAVES_G) {
    const int strip = s*32;
    gll_rows(z3, scr, strip, N, lane);
    bf16x8 bh[2][4];
    #pragma unroll
    for (int nf = 0; nf < 2; ++nf) {
      int node = strip + 16*nf + l15; node = node < N ? node : N-1;
      const char* hr = hB + (size_t)node*256;
      const int sw = (node&7) << 4;
      #pragma unroll
      for (int ks = 0; ks < 4; ++ks)
        bh[nf][ks] = *(const bf16x8*)(hr + ((16*lg + 64*ks) ^ sw));
    }
    VMCNT0;
    bf16x8 bz[2][4];
    read_bfrags(scr, bz, l15, lg);
    f32x4 acc[8][2];
    zacc82(acc);
    gemm128(wSlab, bz, acc, l15, lg);           // qw0a @ z3
    gemm128(wSlab + 32768, bh, acc, l15, lg);   // += qw0b @ h
    ep_lds<0>(acc, qb0, scr, l15, lg);
    bf16x8 bt[2][4];
    read_bfrags(scr, bt, l15, lg);
    f32x4 a2[4][2];
    #pragma unroll
    for (int m = 0; m < 4; ++m)
      #pragma unroll
      for (int n = 0; n < 2; ++n) { f32x4 z = {0.f,0.f,0.f,0.f}; a2[m][n] = z; }
    __builtin_amdgcn_s_setprio(1);
    #pragma unroll
    for (int ks = 0; ks < 4; ++ks)
      #pragma unroll
      for (int mf = 0; mf < 4; ++mf) {
        const int row = 16*mf + l15;
        bf16x8 a = *(const bf16x8*)(wSlab + 65536 + row*256 + ((16*lg + 64*ks) ^ ((row&7)<<4)));
        a2[mf][0] = __builtin_amdgcn_mfma_f32_16x16x32_bf16(a, bt[0][ks], a2[mf][0], 0,0,0);
        a2[mf][1] = __builtin_amdgcn_mfma_f32_16x16x32_bf16(a, bt[1][ks], a2[mf][1], 0,0,0);
      }
    __builtin_amdgcn_s_setprio(0);
    #pragma unroll
    for (int mf = 0; mf < 4; ++mf) {
      const int ch4 = 16*mf + 4*lg;
      const float4 bv = *(const float4*)(qb1 + ch4);
      #pragma unroll
      for (int nf = 0; nf < 2; ++nf) {
        const int node = strip + 16*nf + l15;
        if (node < N) {
          float4 o;
          o.x = tanh_fast(a2[mf][nf][0] + bv.x);
          o.y = tanh_fast(a2[mf][nf][1] + bv.y);
          o.z = tanh_fast(a2[mf][nf][2] + bv.z);
          o.w = tanh_fast(a2[mf][nf][3] + bv.w);
          *(float4*)(out + (size_t)node*64 + ch4) = o;
        }
      }
    }
  }
}

extern "C" void kernel_launch(void* const* d_in, const int* in_sizes, int n_in,
                              void* d_out, int out_size, void* d_ws, size_t ws_size,
                              hipStream_t stream) {
  const float* x   = (const float*)d_in[0];
  const int*   ei  = (const int*)d_in[1];
  const float* ew  = (const float*)d_in[2];
  const float* pw0 = (const float*)d_in[3];
  const float* pb0 = (const float*)d_in[4];
  const float* pw1 = (const float*)d_in[5];
  const float* pb1 = (const float*)d_in[6];
  const float* elw = (const float*)d_in[7];
  const float* elb = (const float*)d_in[8];
  const float* mw0 = (const float*)d_in[9];
  const float* mb0 = (const float*)d_in[10];
  const float* mw1 = (const float*)d_in[11];
  const float* mb1 = (const float*)d_in[12];
  const float* mw2 = (const float*)d_in[13];
  const float* mb2 = (const float*)d_in[14];
  const float* qw0 = (const float*)d_in[15];
  const float* qb0 = (const float*)d_in[16];
  const float* qw1 = (const float*)d_in[17];
  const float* qb1 = (const float*)d_in[18];
  float* out = (float*)d_out;

  int N = in_sizes[0] / 16;
  int E = in_sizes[1] / 2;
  int S = (N + 31) / 32;

  char* p = (char*)d_ws;
  auto alloc = [&](size_t bytes) { char* r = p; p += (bytes + 255) & ~(size_t)255; return r; };
  const size_t rowBytes = (size_t)N * 256;

  char* z3      = alloc(rowBytes);
  int2* recs    = (int2*)alloc((size_t)E * 8);
  int*  deg     = (int*)alloc((size_t)N * 4);
  int*  offs    = (int*)alloc((size_t)N * 4);
  int*  cur     = (int*)alloc((size_t)N * 4);
  int*  part    = (int*)alloc(NBLK * 4);
  int*  bases   = (int*)alloc(NBLK * 4);
  char* wbf     = alloc(WBF_BYTES);

  char* hB;
  if ((size_t)(p - (char*)d_ws) + rowBytes <= ws_size) {
    hB = alloc(rowBytes);
  } else {
    hB = (char*)d_out;  // fallback alias (same per-strip read-before-write discipline)
  }

  void* kargs[] = {
    (void*)&x, (void*)&ei, (void*)&ew,
    (void*)&pw0, (void*)&pb0, (void*)&pw1, (void*)&pb1,
    (void*)&elw, (void*)&elb,
    (void*)&mw0, (void*)&mb0, (void*)&mw1, (void*)&mb1, (void*)&mw2, (void*)&mb2,
    (void*)&qw0, (void*)&qb0, (void*)&qw1, (void*)&qb1,
    (void*)&out, (void*)&hB, (void*)&z3, (void*)&recs,
    (void*)&deg, (void*)&offs, (void*)&cur, (void*)&part, (void*)&bases, (void*)&wbf,
    (void*)&N, (void*)&E, (void*)&S
  };
  hipLaunchCooperativeKernel((const void*)mega_kernel, dim3(NBLK), dim3(NTHR),
                             kargs, 0, stream);
}